// Round 5
// baseline (859.216 us; speedup 1.0000x reference)
//
#include <hip/hip_runtime.h>
#include <stdint.h>

#define N_NODES 100000
#define N_EDGES 1600000
#define IN_C    128
#define OUT_C   64

#define NPB   64                                   // nodes per bucket
#define NBKT  ((N_NODES + NPB - 1) / NPB)          // 1563
#define BCAP  1216                                 // mean 1024, +6 sigma, mult of 64
#define ACHUNK 16384                               // edges per bucketA block
#define NABLK ((N_EDGES + ACHUNK - 1) / ACHUNK)    // 98

// s_waitcnt immediates (gfx9 encoding: vm[3:0]=b3:0, exp=b6:4, lgkm=b11:8, vm[5:4]=b15:14)
#define WAIT_VM0()   __builtin_amdgcn_s_waitcnt(0x0F70)   // vmcnt(0), others free
#define WAIT_LGKM0() __builtin_amdgcn_s_waitcnt(0xC07F)   // lgkmcnt(0), others free

// ---------------- zero bucket cursors ----------------
__global__ void zero_kernel(int* __restrict__ cursor) {
    int i = blockIdx.x * blockDim.x + threadIdx.x;
    if (i < NBKT) cursor[i] = 0;
}

// ---------------- phase A: bucket edges by dst (64 nodes / bucket) ----------
// entry = s*128 + (d & 63)  (7-bit dloc field; row 64 reserved for padding)
__global__ __launch_bounds__(256) void bucketA_kernel(const int* __restrict__ ei,
                                                      int* __restrict__ cursor,
                                                      int* __restrict__ bucket) {
    __shared__ int hist[NBKT];
    __shared__ int base[NBKT];
    __shared__ int hist2[NBKT];
    const int t = threadIdx.x;
    const long long e0 = (long long)blockIdx.x * ACHUNK;
    for (int i = t; i < NBKT; i += 256) { hist[i] = 0; hist2[i] = 0; }
    __syncthreads();
    const int* dsts = ei + N_EDGES;
#pragma unroll
    for (int k = 0; k < ACHUNK / 1024; ++k) {
        long long i4 = e0 / 4 + t + k * 256;
        if (i4 * 4 + 3 < N_EDGES) {
            int4 d = *(const int4*)&dsts[i4 * 4];
            atomicAdd(&hist[d.x >> 6], 1);
            atomicAdd(&hist[d.y >> 6], 1);
            atomicAdd(&hist[d.z >> 6], 1);
            atomicAdd(&hist[d.w >> 6], 1);
        }
    }
    __syncthreads();
    for (int bk = t; bk < NBKT; bk += 256) {
        int c = hist[bk];
        base[bk] = c ? atomicAdd(&cursor[bk], c) : 0;
    }
    __syncthreads();
#pragma unroll
    for (int k = 0; k < ACHUNK / 1024; ++k) {
        long long i4 = e0 / 4 + t + k * 256;
        if (i4 * 4 + 3 < N_EDGES) {
            int4 s4 = *(const int4*)&ei[i4 * 4];
            int4 d4 = *(const int4*)&dsts[i4 * 4];
            int sv[4] = {s4.x, s4.y, s4.z, s4.w};
            int dv[4] = {d4.x, d4.y, d4.z, d4.w};
#pragma unroll
            for (int j = 0; j < 4; ++j) {
                int bk = dv[j] >> 6;
                int pos = base[bk] + atomicAdd(&hist2[bk], 1);
                if (pos < BCAP)
                    bucket[bk * BCAP + pos] = sv[j] * 128 + (dv[j] & (NPB - 1));
            }
        }
    }
}

// -------- degree -> dinv (no global atomics) + pad buckets to mult of 64 -----
__global__ __launch_bounds__(256) void bdeg_kernel(const int* __restrict__ cursor,
                                                   int* __restrict__ bucket,
                                                   float* __restrict__ dinv) {
    __shared__ int hist[NPB];
    const int t = threadIdx.x, b = blockIdx.x;
    if (t < NPB) hist[t] = 0;
    __syncthreads();
    int m = cursor[b]; if (m > BCAP) m = BCAP;
    int* bb = bucket + b * BCAP;
    for (int i = t; i < m; i += 256) atomicAdd(&hist[bb[i] & 127], 1);
    // pad to multiple of 64 with sentinel (s=0, row=64 -> trash row)
    int mp = (m + 63) & ~63;
    for (int i = m + t; i < mp; i += 256) bb[i] = 64;
    __syncthreads();
    if (t < NPB) {
        int n = b * NPB + t;
        if (n < N_NODES) dinv[n] = rsqrtf((float)hist[t] + 1.0f);   // +1 self-loop
    }
}

// ---------------- xws = dinv[n] * (x @ W) : 32 nodes/block ----------------
#define XN  32
#define SXS 132
__global__ __launch_bounds__(256) void xws_kernel(const float* __restrict__ x,
                                                  const float* __restrict__ W,
                                                  const float* __restrict__ dinv,
                                                  float* __restrict__ xws) {
    __shared__ float sW[IN_C * OUT_C];     // 32 KB
    __shared__ float sx[XN * SXS];         // 16.9 KB
    const int t = threadIdx.x;
    const int n0 = blockIdx.x * XN;
    const float4* W4 = (const float4*)W;
    float4* sW4 = (float4*)sW;
#pragma unroll
    for (int k = 0; k < 8; ++k) sW4[t + k * 256] = W4[t + k * 256];
#pragma unroll
    for (int k = 0; k < 4; ++k) {
        int idx = (t + k * 256) * 4;
        int r = idx >> 7, kk = idx & 127;
        int n = n0 + r;
        float4 v = (n < N_NODES) ? *(const float4*)&x[(long long)n * IN_C + kk]
                                 : make_float4(0.f, 0.f, 0.f, 0.f);
        *(float4*)&sx[r * SXS + kk] = v;
    }
    __syncthreads();
    const int r  = t >> 4;
    const int cq = (t & 15) << 2;
    float4 a0 = make_float4(0.f,0.f,0.f,0.f), a1 = a0;
#pragma unroll 8
    for (int k = 0; k < IN_C; ++k) {
        float x0 = sx[r * SXS + k];
        float x1 = sx[(r + 16) * SXS + k];
        float4 wv = *(const float4*)&sW[(k << 6) + cq];
        a0.x = fmaf(x0, wv.x, a0.x); a0.y = fmaf(x0, wv.y, a0.y);
        a0.z = fmaf(x0, wv.z, a0.z); a0.w = fmaf(x0, wv.w, a0.w);
        a1.x = fmaf(x1, wv.x, a1.x); a1.y = fmaf(x1, wv.y, a1.y);
        a1.z = fmaf(x1, wv.z, a1.z); a1.w = fmaf(x1, wv.w, a1.w);
    }
    int na = n0 + r, nb = n0 + r + 16;
    if (na < N_NODES) {
        float di = dinv[na];
        a0.x *= di; a0.y *= di; a0.z *= di; a0.w *= di;
        *(float4*)&xws[(long long)na * OUT_C + cq] = a0;
    }
    if (nb < N_NODES) {
        float di = dinv[nb];
        a1.x *= di; a1.y *= di; a1.z *= di; a1.w *= di;
        *(float4*)&xws[(long long)nb * OUT_C + cq] = a1;
    }
}

// ------ fused aggregate + epilogue: global_load_lds DMA staging pipeline -----
// Per entry: DMA the 256B xws row into per-wave LDS stage (no VGPRs involved,
// 32 in flight), then ds_read stage + ds_add into sAgg (conflict-free).
__global__ __launch_bounds__(256) void aggb_kernel(const int* __restrict__ cursor,
                                                   const int* __restrict__ bucket,
                                                   const float* __restrict__ dinv,
                                                   const float* __restrict__ xws,
                                                   const float* __restrict__ b,
                                                   const float* __restrict__ Wc,
                                                   const float* __restrict__ bc,
                                                   float4* __restrict__ pq) {
    __shared__ float sAgg[65 * OUT_C];        // 16.6 KB, row 64 = pad trash
    __shared__ float stage[4][32][64];        // 32 KB: per-wave 32-slot ring
    const int t = threadIdx.x, bk = blockIdx.x;
    const int wave = t >> 6, lane = t & 63;
    float4* sA4 = (float4*)sAgg;
    for (int k = t; k < 65 * OUT_C / 4; k += 256)
        sA4[k] = make_float4(0.f, 0.f, 0.f, 0.f);
    __syncthreads();
    int m = cursor[bk]; if (m > BCAP) m = BCAP;
    int mp = (m + 63) & ~63;                  // padded by bdeg
    const int* bb = bucket + bk * BCAP;
    float* st = &stage[wave][0][0];
    for (int i0 = wave * 64; i0 < mp; i0 += 256) {
        int ent = bb[i0 + lane];              // 64 entries, coalesced
        for (int j = 0; j < 64; j += 32) {
            WAIT_LGKM0();                     // prev group's stage reads done (WAR)
#pragma unroll
            for (int u = 0; u < 32; ++u) {
                int e = __builtin_amdgcn_readlane(ent, j + u);
                const float* gp = xws + ((unsigned)e >> 7) * OUT_C + lane;
                __builtin_amdgcn_global_load_lds(
                    (const __attribute__((address_space(1))) void*)gp,
                    (__attribute__((address_space(3))) void*)(st + u * 64),
                    4, 0, 0);
            }
            WAIT_VM0();                       // DMA data landed in LDS
#pragma unroll
            for (int u = 0; u < 32; ++u) {
                int e = __builtin_amdgcn_readlane(ent, j + u);
                atomicAdd(&sAgg[(e & 127) * OUT_C + lane], st[u * 64 + lane]);
            }
        }
    }
    __syncthreads();
    float wc0 = Wc[2 * lane],           wc1 = Wc[2 * lane + 1];
    float wc2 = Wc[2 * (OUT_C + lane)], wc3 = Wc[2 * (OUT_C + lane) + 1];
    float bias = b[lane], bc0 = bc[0], bc1 = bc[1];
    for (int r = wave; r < NPB; r += 4) {
        int n = bk * NPB + r;
        if (n >= N_NODES) break;
        float a = sAgg[r * OUT_C + lane] + xws[(long long)n * OUT_C + lane];
        float h = fmaxf(fmaf(dinv[n], a, bias), 0.f);
        float p0 = h * wc0, p1 = h * wc1, q0 = h * wc2, q1 = h * wc3;
#pragma unroll
        for (int off = 32; off; off >>= 1) {
            p0 += __shfl_down(p0, off); p1 += __shfl_down(p1, off);
            q0 += __shfl_down(q0, off); q1 += __shfl_down(q1, off);
        }
        if (lane == 0) pq[n] = make_float4(p0 + bc0, p1 + bc1, q0, q1);
    }
}

// ---------------- edge outputs: out[e] = p[src] + q[dst] ----------------
__global__ void edge_kernel(const int* __restrict__ ei, const int* __restrict__ nei,
                            const float4* __restrict__ pq, float4* __restrict__ out4) {
    int idx = blockIdx.x * blockDim.x + threadIdx.x;   // 2 edges per thread
    if (idx >= N_EDGES) return;
    int e2 = idx * 2;
    int2 ss, dd;
    if (e2 < N_EDGES) {
        ss = *(const int2*)&ei[e2];
        dd = *(const int2*)&ei[N_EDGES + e2];
    } else {
        int f = e2 - N_EDGES;
        ss = *(const int2*)&nei[f];
        dd = *(const int2*)&nei[N_EDGES + f];
    }
    float4 pa = pq[ss.x], qa = pq[dd.x];
    float4 pb = pq[ss.y], qb = pq[dd.y];
    out4[idx] = make_float4(pa.x + qa.z, pa.y + qa.w, pb.x + qb.z, pb.y + qb.w);
}

extern "C" void kernel_launch(void* const* d_in, const int* in_sizes, int n_in,
                              void* d_out, int out_size, void* d_ws, size_t ws_size,
                              hipStream_t stream) {
    const float* x   = (const float*)d_in[0];   // [N,128]
    const int*   ei  = (const int*)  d_in[1];   // [2,E]
    const int*   nei = (const int*)  d_in[2];   // [2,E]
    const float* W   = (const float*)d_in[3];   // [128,64]
    const float* b   = (const float*)d_in[4];   // [64]
    const float* Wc  = (const float*)d_in[5];   // [128,2]
    const float* bc  = (const float*)d_in[6];   // [2]

    // workspace (ints): end = 6901952 + 1563*1216 = 8802560 ints = 35.2 MB
    int*   wsI    = (int*)d_ws;
    float* dinv   = (float*)wsI;                 // N          [0, 100352)
    float* xws    = (float*)(wsI + 100352);      // N*64       [100352, 6500352)
    float* pq     = (float*)(wsI + 6500352);     // N*4        [6500352, 6900352)
    int*   cursor = wsI + 6900352;               // NBKT       [6900352, 6901915)
    int*   bucket = wsI + 6901952;               // NBKT*BCAP

    const int B = 256;
    zero_kernel<<<(NBKT + B - 1) / B, B, 0, stream>>>(cursor);
    bucketA_kernel<<<NABLK, B, 0, stream>>>(ei, cursor, bucket);
    bdeg_kernel<<<NBKT, B, 0, stream>>>(cursor, bucket, dinv);
    xws_kernel<<<(N_NODES + XN - 1) / XN, B, 0, stream>>>(x, W, dinv, xws);
    aggb_kernel<<<NBKT, B, 0, stream>>>(cursor, bucket, dinv, xws, b, Wc, bc,
                                        (float4*)pq);
    edge_kernel<<<(N_EDGES + B - 1) / B, B, 0, stream>>>(ei, nei, (const float4*)pq,
                                                         (float4*)d_out);
}

// Round 6
// 274.206 us; speedup vs baseline: 3.1335x; 3.1335x over previous
//
#include <hip/hip_runtime.h>
#include <stdint.h>

#define N_NODES 100000
#define N_EDGES 1600000
#define IN_C    128
#define OUT_C   64

#define NPB   64                                   // nodes per bucket
#define NBKT  ((N_NODES + NPB - 1) / NPB)          // 1563
#define BCAP  1216                                 // mean 1024, +6 sigma
#define ACHUNK 8192                                // edges per bucketA block
#define NABLK ((N_EDGES + ACHUNK - 1) / ACHUNK)    // 196

// ---------------- zero bucket cursors ----------------
__global__ void zero_kernel(int* __restrict__ cursor) {
    int i = blockIdx.x * blockDim.x + threadIdx.x;
    if (i < NBKT) cursor[i] = 0;
}

// ---------------- phase A: bucket edges by dst (64 nodes / bucket) ----------
// entry = s*128 + (d & 63)
__global__ __launch_bounds__(256) void bucketA_kernel(const int* __restrict__ ei,
                                                      int* __restrict__ cursor,
                                                      int* __restrict__ bucket) {
    __shared__ int hist[NBKT];
    __shared__ int base[NBKT];
    __shared__ int hist2[NBKT];
    const int t = threadIdx.x;
    const long long e0 = (long long)blockIdx.x * ACHUNK;
    for (int i = t; i < NBKT; i += 256) { hist[i] = 0; hist2[i] = 0; }
    __syncthreads();
    const int* dsts = ei + N_EDGES;
#pragma unroll
    for (int k = 0; k < ACHUNK / 1024; ++k) {
        long long i4 = e0 / 4 + t + k * 256;
        if (i4 * 4 + 3 < N_EDGES) {
            int4 d = *(const int4*)&dsts[i4 * 4];
            atomicAdd(&hist[d.x >> 6], 1);
            atomicAdd(&hist[d.y >> 6], 1);
            atomicAdd(&hist[d.z >> 6], 1);
            atomicAdd(&hist[d.w >> 6], 1);
        }
    }
    __syncthreads();
    for (int bk = t; bk < NBKT; bk += 256) {
        int c = hist[bk];
        base[bk] = c ? atomicAdd(&cursor[bk], c) : 0;
    }
    __syncthreads();
#pragma unroll
    for (int k = 0; k < ACHUNK / 1024; ++k) {
        long long i4 = e0 / 4 + t + k * 256;
        if (i4 * 4 + 3 < N_EDGES) {
            int4 s4 = *(const int4*)&ei[i4 * 4];
            int4 d4 = *(const int4*)&dsts[i4 * 4];
            int sv[4] = {s4.x, s4.y, s4.z, s4.w};
            int dv[4] = {d4.x, d4.y, d4.z, d4.w};
#pragma unroll
            for (int j = 0; j < 4; ++j) {
                int bk = dv[j] >> 6;
                int pos = base[bk] + atomicAdd(&hist2[bk], 1);
                if (pos < BCAP)
                    bucket[bk * BCAP + pos] = sv[j] * 128 + (dv[j] & (NPB - 1));
            }
        }
    }
}

// ----- per-bucket: histogram + prefix + in-place sort-by-node -> CSR ---------
// After this, bucket[bkt*BCAP + rowbeg..rowend) holds plain src ids per node.
__global__ __launch_bounds__(256) void bdegcsr_kernel(const int* __restrict__ cursor,
                                                      int* __restrict__ bucket,
                                                      float* __restrict__ dinv,
                                                      int* __restrict__ rowbeg,
                                                      int* __restrict__ rowend) {
    __shared__ int hist[NPB];
    __shared__ int pref[NPB + 1];
    __shared__ int cur[NPB];
    __shared__ int sorted[BCAP];
    const int t = threadIdx.x, b = blockIdx.x;
    if (t < NPB) { hist[t] = 0; cur[t] = 0; }
    __syncthreads();
    int m = cursor[b]; if (m > BCAP) m = BCAP;
    int* bb = bucket + b * BCAP;
    for (int i = t; i < m; i += 256) atomicAdd(&hist[bb[i] & 127], 1);
    __syncthreads();
    if (t == 0) {                       // 64-wide serial prefix: negligible
        int s = 0;
#pragma unroll
        for (int k = 0; k < NPB; ++k) { pref[k] = s; s += hist[k]; }
        pref[NPB] = s;
    }
    __syncthreads();
    for (int i = t; i < m; i += 256) {
        int e = bb[i];
        int dl = e & 127;
        int pos = pref[dl] + atomicAdd(&cur[dl], 1);
        sorted[pos] = e >> 7;           // plain src id
    }
    __syncthreads();
    for (int i = t; i < m; i += 256) bb[i] = sorted[i];   // coalesced writeback
    if (t < NPB) {
        int n = b * NPB + t;
        if (n < N_NODES) {
            rowbeg[n] = b * BCAP + pref[t];
            rowend[n] = b * BCAP + pref[t + 1];
            dinv[n]   = rsqrtf((float)hist[t] + 1.0f);    // +1 self-loop
        }
    }
}

// ---------------- xws = dinv[n] * (x @ W) : 32 nodes/block ----------------
#define XN  32
#define SXS 132
__global__ __launch_bounds__(256) void xws_kernel(const float* __restrict__ x,
                                                  const float* __restrict__ W,
                                                  const float* __restrict__ dinv,
                                                  float* __restrict__ xws) {
    __shared__ float sW[IN_C * OUT_C];     // 32 KB
    __shared__ float sx[XN * SXS];         // 16.9 KB
    const int t = threadIdx.x;
    const int n0 = blockIdx.x * XN;
    const float4* W4 = (const float4*)W;
    float4* sW4 = (float4*)sW;
#pragma unroll
    for (int k = 0; k < 8; ++k) sW4[t + k * 256] = W4[t + k * 256];
#pragma unroll
    for (int k = 0; k < 4; ++k) {
        int idx = (t + k * 256) * 4;
        int r = idx >> 7, kk = idx & 127;
        int n = n0 + r;
        float4 v = (n < N_NODES) ? *(const float4*)&x[(long long)n * IN_C + kk]
                                 : make_float4(0.f, 0.f, 0.f, 0.f);
        *(float4*)&sx[r * SXS + kk] = v;
    }
    __syncthreads();
    const int r  = t >> 4;
    const int cq = (t & 15) << 2;
    float4 a0 = make_float4(0.f,0.f,0.f,0.f), a1 = a0;
#pragma unroll 8
    for (int k = 0; k < IN_C; ++k) {
        float x0 = sx[r * SXS + k];
        float x1 = sx[(r + 16) * SXS + k];
        float4 wv = *(const float4*)&sW[(k << 6) + cq];
        a0.x = fmaf(x0, wv.x, a0.x); a0.y = fmaf(x0, wv.y, a0.y);
        a0.z = fmaf(x0, wv.z, a0.z); a0.w = fmaf(x0, wv.w, a0.w);
        a1.x = fmaf(x1, wv.x, a1.x); a1.y = fmaf(x1, wv.y, a1.y);
        a1.z = fmaf(x1, wv.z, a1.z); a1.w = fmaf(x1, wv.w, a1.w);
    }
    int na = n0 + r, nb = n0 + r + 16;
    if (na < N_NODES) {
        float di = dinv[na];
        a0.x *= di; a0.y *= di; a0.z *= di; a0.w *= di;
        *(float4*)&xws[(long long)na * OUT_C + cq] = a0;
    }
    if (nb < N_NODES) {
        float di = dinv[nb];
        a1.x *= di; a1.y *= di; a1.z *= di; a1.w *= di;
        *(float4*)&xws[(long long)nb * OUT_C + cq] = a1;
    }
}

// ------- pull aggregation + fused epilogue: wave per node (R2 structure) -----
// acc = sum_s xws[s]; h = relu(dinv[n]*(acc + xws[n]) + b); pq[n] = h@Wc (+bc)
__global__ __launch_bounds__(256) void aggnode_kernel(
    const int* __restrict__ rowbeg, const int* __restrict__ rowend,
    const int* __restrict__ srcs, const float* __restrict__ dinv,
    const float* __restrict__ xws, const float* __restrict__ b,
    const float* __restrict__ Wc, const float* __restrict__ bc,
    float4* __restrict__ pq) {
    const int lane = threadIdx.x & 63;
    const int node = blockIdx.x * 4 + (threadIdx.x >> 6);
    if (node >= N_NODES) return;
    const int beg = rowbeg[node], end = rowend[node];
    const int c = lane;
    float a0 = 0.f, a1 = 0.f, a2 = 0.f, a3 = 0.f;
    float a4 = 0.f, a5 = 0.f, a6 = 0.f, a7 = 0.f;
    for (int i = beg; i < end; i += 64) {
        int cnt = end - i;
        if (cnt > 64) cnt = 64;
        int sv = (lane < cnt) ? srcs[i + lane] : 0;   // coalesced list load
        int j = 0;
        for (; j + 7 < cnt; j += 8) {                 // 8 independent gathers
            int s0 = __shfl(sv, j),     s1 = __shfl(sv, j + 1);
            int s2 = __shfl(sv, j + 2), s3 = __shfl(sv, j + 3);
            int s4 = __shfl(sv, j + 4), s5 = __shfl(sv, j + 5);
            int s6 = __shfl(sv, j + 6), s7 = __shfl(sv, j + 7);
            float x0 = xws[s0 * OUT_C + c], x1 = xws[s1 * OUT_C + c];
            float x2 = xws[s2 * OUT_C + c], x3 = xws[s3 * OUT_C + c];
            float x4 = xws[s4 * OUT_C + c], x5 = xws[s5 * OUT_C + c];
            float x6 = xws[s6 * OUT_C + c], x7 = xws[s7 * OUT_C + c];
            a0 += x0; a1 += x1; a2 += x2; a3 += x3;
            a4 += x4; a5 += x5; a6 += x6; a7 += x7;
        }
        for (; j < cnt; ++j) {
            int s = __shfl(sv, j);
            a0 += xws[s * OUT_C + c];
        }
    }
    float acc = ((a0 + a1) + (a2 + a3)) + ((a4 + a5) + (a6 + a7));
    acc += xws[(long long)node * OUT_C + c];          // self-loop (dinv folded)
    float h = fmaxf(fmaf(dinv[node], acc, b[c]), 0.f);
    float p0 = h * Wc[2 * c + 0],           p1 = h * Wc[2 * c + 1];
    float q0 = h * Wc[2 * (OUT_C + c) + 0], q1 = h * Wc[2 * (OUT_C + c) + 1];
#pragma unroll
    for (int off = 32; off; off >>= 1) {
        p0 += __shfl_down(p0, off); p1 += __shfl_down(p1, off);
        q0 += __shfl_down(q0, off); q1 += __shfl_down(q1, off);
    }
    if (lane == 0) pq[node] = make_float4(p0 + bc[0], p1 + bc[1], q0, q1);
}

// ---------------- edge outputs: out[e] = p[src] + q[dst] ----------------
__global__ void edge_kernel(const int* __restrict__ ei, const int* __restrict__ nei,
                            const float4* __restrict__ pq, float4* __restrict__ out4) {
    int idx = blockIdx.x * blockDim.x + threadIdx.x;   // 2 edges per thread
    if (idx >= N_EDGES) return;
    int e2 = idx * 2;
    int2 ss, dd;
    if (e2 < N_EDGES) {
        ss = *(const int2*)&ei[e2];
        dd = *(const int2*)&ei[N_EDGES + e2];
    } else {
        int f = e2 - N_EDGES;
        ss = *(const int2*)&nei[f];
        dd = *(const int2*)&nei[N_EDGES + f];
    }
    float4 pa = pq[ss.x], qa = pq[dd.x];
    float4 pb = pq[ss.y], qb = pq[dd.y];
    out4[idx] = make_float4(pa.x + qa.z, pa.y + qa.w, pb.x + qb.z, pb.y + qb.w);
}

extern "C" void kernel_launch(void* const* d_in, const int* in_sizes, int n_in,
                              void* d_out, int out_size, void* d_ws, size_t ws_size,
                              hipStream_t stream) {
    const float* x   = (const float*)d_in[0];   // [N,128]
    const int*   ei  = (const int*)  d_in[1];   // [2,E]
    const int*   nei = (const int*)  d_in[2];   // [2,E]
    const float* W   = (const float*)d_in[3];   // [128,64]
    const float* b   = (const float*)d_in[4];   // [64]
    const float* Wc  = (const float*)d_in[5];   // [128,2]
    const float* bc  = (const float*)d_in[6];   // [2]

    // workspace (ints): end = 7102656 + 1563*1216 = 9003264 ints = 36.0 MB
    int*   wsI    = (int*)d_ws;
    float* dinv   = (float*)wsI;                 // N          [0, 100352)
    float* xws    = (float*)(wsI + 100352);      // N*64       [100352, 6500352)
    float* pq     = (float*)(wsI + 6500352);     // N*4        [6500352, 6900352)
    int*   cursor = wsI + 6900352;               // NBKT       [6900352, 6901952)
    int*   rowbeg = wsI + 6901952;               // N          [6901952, 7002304)
    int*   rowend = wsI + 7002304;               // N          [7002304, 7102656)
    int*   bucket = wsI + 7102656;               // NBKT*BCAP

    const int B = 256;
    zero_kernel<<<(NBKT + B - 1) / B, B, 0, stream>>>(cursor);
    bucketA_kernel<<<NABLK, B, 0, stream>>>(ei, cursor, bucket);
    bdegcsr_kernel<<<NBKT, B, 0, stream>>>(cursor, bucket, dinv, rowbeg, rowend);
    xws_kernel<<<(N_NODES + XN - 1) / XN, B, 0, stream>>>(x, W, dinv, xws);
    aggnode_kernel<<<(N_NODES + 3) / 4, B, 0, stream>>>(rowbeg, rowend, bucket, dinv,
                                                        xws, b, Wc, bc, (float4*)pq);
    edge_kernel<<<(N_EDGES + B - 1) / B, B, 0, stream>>>(ei, nei, (const float4*)pq,
                                                         (float4*)d_out);
}

// Round 7
// 270.609 us; speedup vs baseline: 3.1751x; 1.0133x over previous
//
#include <hip/hip_runtime.h>

#define N_NODES 100000
#define N_EDGES 1600000
#define IN_C    128
#define OUT_C   64

#define SB_NODES 1024                              // nodes per super-bucket
#define NSB  ((N_NODES + SB_NODES - 1) / SB_NODES) // 98
#define SCAP 17408                                 // mean 16327, +8 sigma
#define ACHUNK 8192                                // edges per sorta block
#define NABLK ((N_EDGES + ACHUNK - 1) / ACHUNK)    // 196

// ---- bf16x2 helpers ----
__device__ inline unsigned pack_bf16x2(float lo, float hi) {
    unsigned a = __float_as_uint(lo), b2 = __float_as_uint(hi);
    a  += 0x7fff + ((a  >> 16) & 1);               // RNE
    b2 += 0x7fff + ((b2 >> 16) & 1);
    return (a >> 16) | (b2 & 0xffff0000u);
}
__device__ inline float bf_lo(unsigned v) { return __uint_as_float(v << 16); }
__device__ inline float bf_hi(unsigned v) { return __uint_as_float(v & 0xffff0000u); }

// ---------------- zero super-bucket cursors ----------------
__global__ void zero_kernel(int* __restrict__ cursor) {
    int i = blockIdx.x * blockDim.x + threadIdx.x;
    if (i < NSB) cursor[i] = 0;
}

// ------ pass A: partition edges into 98 coarse dst-buckets (1024 nodes) -----
// entry = s*1024 + (d & 1023); chunked reservations avg ~84 entries = no
// 64B-line false sharing (the R2/R6 scatter pathology).
__global__ __launch_bounds__(256) void sorta_kernel(const int* __restrict__ ei,
                                                    int* __restrict__ cursor,
                                                    int* __restrict__ sb) {
    __shared__ int hist[NSB];
    __shared__ int base_[NSB];
    __shared__ int cur[NSB];
    const int t = threadIdx.x;
    const long long e0 = (long long)blockIdx.x * ACHUNK;
    if (t < NSB) { hist[t] = 0; cur[t] = 0; }
    __syncthreads();
    const int* dsts = ei + N_EDGES;
#pragma unroll
    for (int k = 0; k < ACHUNK / 1024; ++k) {
        long long i4 = e0 / 4 + t + k * 256;
        if (i4 * 4 + 3 < N_EDGES) {
            int4 d = *(const int4*)&dsts[i4 * 4];
            atomicAdd(&hist[d.x >> 10], 1);
            atomicAdd(&hist[d.y >> 10], 1);
            atomicAdd(&hist[d.z >> 10], 1);
            atomicAdd(&hist[d.w >> 10], 1);
        }
    }
    __syncthreads();
    if (t < NSB) {
        int c = hist[t];
        base_[t] = c ? atomicAdd(&cursor[t], c) : 0;
    }
    __syncthreads();
#pragma unroll
    for (int k = 0; k < ACHUNK / 1024; ++k) {
        long long i4 = e0 / 4 + t + k * 256;
        if (i4 * 4 + 3 < N_EDGES) {
            int4 s4 = *(const int4*)&ei[i4 * 4];
            int4 d4 = *(const int4*)&dsts[i4 * 4];
            int sv[4] = {s4.x, s4.y, s4.z, s4.w};
            int dv[4] = {d4.x, d4.y, d4.z, d4.w};
#pragma unroll
            for (int j = 0; j < 4; ++j) {
                int bk = dv[j] >> 10;
                int pos = base_[bk] + atomicAdd(&cur[bk], 1);
                if (pos < SCAP)
                    sb[bk * SCAP + pos] = sv[j] * SB_NODES + (dv[j] & (SB_NODES - 1));
            }
        }
    }
}

// ------ pass B: per coarse bucket, LDS counting sort by node -> CSR ---------
// Emits dst-sorted src ids in place + rowbeg/rowend/dinv. One block per bucket.
__global__ __launch_bounds__(256) void sortb_kernel(const int* __restrict__ cursor,
                                                    int* __restrict__ sb,
                                                    float* __restrict__ dinv,
                                                    int* __restrict__ rowbeg,
                                                    int* __restrict__ rowend) {
    __shared__ int hist[SB_NODES];
    __shared__ int pref[SB_NODES + 1];
    __shared__ int cur[SB_NODES];
    __shared__ int sc[256];
    __shared__ int sorted[SCAP];                   // 69.6 KB
    const int t = threadIdx.x, b = blockIdx.x;
    for (int k = t; k < SB_NODES; k += 256) { hist[k] = 0; cur[k] = 0; }
    __syncthreads();
    int m = cursor[b]; if (m > SCAP) m = SCAP;
    int* bb = sb + b * SCAP;
    for (int i = t; i < m; i += 256) atomicAdd(&hist[bb[i] & (SB_NODES - 1)], 1);
    __syncthreads();
    int c0 = hist[4 * t], c1 = hist[4 * t + 1], c2 = hist[4 * t + 2], c3 = hist[4 * t + 3];
    int tsum = c0 + c1 + c2 + c3;
    sc[t] = tsum;
    __syncthreads();
    for (int off = 1; off < 256; off <<= 1) {      // Hillis-Steele inclusive
        int u = (t >= off) ? sc[t - off] : 0;
        __syncthreads();
        sc[t] += u;
        __syncthreads();
    }
    int excl = sc[t] - tsum;
    pref[4 * t]     = excl;
    pref[4 * t + 1] = excl + c0;
    pref[4 * t + 2] = excl + c0 + c1;
    pref[4 * t + 3] = excl + c0 + c1 + c2;
    if (t == 255) pref[SB_NODES] = sc[255];
    __syncthreads();
    for (int i = t; i < m; i += 256) {
        int e = bb[i];
        int dl = e & (SB_NODES - 1);
        int pos = pref[dl] + atomicAdd(&cur[dl], 1);
        sorted[pos] = e >> 10;                     // plain src id
    }
    __syncthreads();
    for (int i = t; i < m; i += 256) bb[i] = sorted[i];   // coalesced writeback
    for (int k = t; k < SB_NODES; k += 256) {
        int n = b * SB_NODES + k;
        if (n < N_NODES) {
            rowbeg[n] = b * SCAP + pref[k];
            rowend[n] = b * SCAP + pref[k + 1];
            dinv[n]   = rsqrtf((float)hist[k] + 1.0f);    // +1 self-loop
        }
    }
}

// ------- xws = bf16( dinv[n] * (x @ W) ) : 32 nodes/block, 128 B rows -------
#define XN  32
#define SXS 132
__global__ __launch_bounds__(256) void xws_kernel(const float* __restrict__ x,
                                                  const float* __restrict__ W,
                                                  const float* __restrict__ dinv,
                                                  unsigned* __restrict__ xwsh) {
    __shared__ float sW[IN_C * OUT_C];     // 32 KB
    __shared__ float sx[XN * SXS];         // 16.9 KB
    const int t = threadIdx.x;
    const int n0 = blockIdx.x * XN;
    const float4* W4 = (const float4*)W;
    float4* sW4 = (float4*)sW;
#pragma unroll
    for (int k = 0; k < 8; ++k) sW4[t + k * 256] = W4[t + k * 256];
#pragma unroll
    for (int k = 0; k < 4; ++k) {
        int idx = (t + k * 256) * 4;
        int r = idx >> 7, kk = idx & 127;
        int n = n0 + r;
        float4 v = (n < N_NODES) ? *(const float4*)&x[(long long)n * IN_C + kk]
                                 : make_float4(0.f, 0.f, 0.f, 0.f);
        *(float4*)&sx[r * SXS + kk] = v;
    }
    __syncthreads();
    const int r  = t >> 4;
    const int cq = (t & 15) << 2;
    float4 a0 = make_float4(0.f,0.f,0.f,0.f), a1 = a0;
#pragma unroll 8
    for (int k = 0; k < IN_C; ++k) {
        float x0 = sx[r * SXS + k];
        float x1 = sx[(r + 16) * SXS + k];
        float4 wv = *(const float4*)&sW[(k << 6) + cq];
        a0.x = fmaf(x0, wv.x, a0.x); a0.y = fmaf(x0, wv.y, a0.y);
        a0.z = fmaf(x0, wv.z, a0.z); a0.w = fmaf(x0, wv.w, a0.w);
        a1.x = fmaf(x1, wv.x, a1.x); a1.y = fmaf(x1, wv.y, a1.y);
        a1.z = fmaf(x1, wv.z, a1.z); a1.w = fmaf(x1, wv.w, a1.w);
    }
    int na = n0 + r, nb = n0 + r + 16;
    if (na < N_NODES) {
        float di = dinv[na];
        uint2 o = make_uint2(pack_bf16x2(a0.x * di, a0.y * di),
                             pack_bf16x2(a0.z * di, a0.w * di));
        *(uint2*)&xwsh[(long long)na * 32 + ((t & 15) << 1)] = o;
    }
    if (nb < N_NODES) {
        float di = dinv[nb];
        uint2 o = make_uint2(pack_bf16x2(a1.x * di, a1.y * di),
                             pack_bf16x2(a1.z * di, a1.w * di));
        *(uint2*)&xwsh[(long long)nb * 32 + ((t & 15) << 1)] = o;
    }
}

// ------- pull aggregation + fused epilogue: wave per node, 2 edges/request --
// lanes 0-31 gather edge j's 128B bf16 row, lanes 32-63 edge j+1's.
__global__ __launch_bounds__(256) void aggnode_kernel(
    const int* __restrict__ rowbeg, const int* __restrict__ rowend,
    const int* __restrict__ srcs, const float* __restrict__ dinv,
    const unsigned* __restrict__ xwsh, const float* __restrict__ b,
    const float* __restrict__ Wc, const float* __restrict__ bc,
    float4* __restrict__ pq) {
    const int lane = threadIdx.x & 63;
    const int node = blockIdx.x * 4 + (threadIdx.x >> 6);
    if (node >= N_NODES) return;
    const int beg = rowbeg[node], end = rowend[node];
    const int half = lane >> 5, hl = lane & 31;    // dword hl of row
    float ax0 = 0.f, ay0 = 0.f, ax1 = 0.f, ay1 = 0.f;
    float ax2 = 0.f, ay2 = 0.f, ax3 = 0.f, ay3 = 0.f;
    for (int i = beg; i < end; i += 64) {
        int cnt = end - i;
        if (cnt > 64) cnt = 64;
        int sv = (lane < cnt) ? srcs[i + lane] : 0;
        int j = 0;
        for (; j + 15 < cnt; j += 16) {            // 8 loads = 16 edges
#pragma unroll
            for (int u = 0; u < 8; ++u) {
                int s = __shfl(sv, j + 2 * u + half);
                unsigned v = xwsh[s * 32 + hl];
                float lo = bf_lo(v), hi = bf_hi(v);
                if (u == 0 || u == 4) { ax0 += lo; ay0 += hi; }
                else if (u == 1 || u == 5) { ax1 += lo; ay1 += hi; }
                else if (u == 2 || u == 6) { ax2 += lo; ay2 += hi; }
                else { ax3 += lo; ay3 += hi; }
            }
        }
        for (; j + 1 < cnt; j += 2) {              // pair tail
            int s = __shfl(sv, j + half);
            unsigned v = xwsh[s * 32 + hl];
            ax0 += bf_lo(v); ay0 += bf_hi(v);
        }
        if (j < cnt) {                             // single-edge tail
            int s = __shfl(sv, j);
            if (lane < 32) {
                unsigned v = xwsh[s * 32 + hl];
                ax1 += bf_lo(v); ay1 += bf_hi(v);
            }
        }
    }
    float ax = (ax0 + ax1) + (ax2 + ax3);
    float ay = (ay0 + ay1) + (ay2 + ay3);
    // combine the two 32-lane halves (lanes 0-31 hold the result)
    ax += __shfl(ax, lane + 32);
    ay += __shfl(ay, lane + 32);
    // self-loop (dinv folded into xwsh)
    unsigned vs = xwsh[node * 32 + hl];
    ax += bf_lo(vs); ay += bf_hi(vs);
    float di = dinv[node];
    float2 b2 = ((const float2*)b)[hl];            // b[2hl], b[2hl+1]
    float h0 = fmaxf(fmaf(di, ax, b2.x), 0.f);
    float h1 = fmaxf(fmaf(di, ay, b2.y), 0.f);
    float4 wcs = ((const float4*)Wc)[hl];          // Wc rows 2hl,2hl+1 (src half)
    float4 wcd = ((const float4*)(Wc + 2 * OUT_C))[hl];   // dst half
    float p0 = h0 * wcs.x + h1 * wcs.z;
    float p1 = h0 * wcs.y + h1 * wcs.w;
    float q0 = h0 * wcd.x + h1 * wcd.z;
    float q1 = h0 * wcd.y + h1 * wcd.w;
#pragma unroll
    for (int off = 16; off; off >>= 1) {           // width-32 reduce (lanes 0-31)
        p0 += __shfl_down(p0, off); p1 += __shfl_down(p1, off);
        q0 += __shfl_down(q0, off); q1 += __shfl_down(q1, off);
    }
    if (lane == 0) pq[node] = make_float4(p0 + bc[0], p1 + bc[1], q0, q1);
}

// ---------------- edge outputs: out[e] = p[src] + q[dst] ----------------
__global__ void edge_kernel(const int* __restrict__ ei, const int* __restrict__ nei,
                            const float4* __restrict__ pq, float4* __restrict__ out4) {
    int idx = blockIdx.x * blockDim.x + threadIdx.x;   // 2 edges per thread
    if (idx >= N_EDGES) return;
    int e2 = idx * 2;
    int2 ss, dd;
    if (e2 < N_EDGES) {
        ss = *(const int2*)&ei[e2];
        dd = *(const int2*)&ei[N_EDGES + e2];
    } else {
        int f = e2 - N_EDGES;
        ss = *(const int2*)&nei[f];
        dd = *(const int2*)&nei[N_EDGES + f];
    }
    float4 pa = pq[ss.x], qa = pq[dd.x];
    float4 pb = pq[ss.y], qb = pq[dd.y];
    out4[idx] = make_float4(pa.x + qa.z, pa.y + qa.w, pb.x + qb.z, pb.y + qb.w);
}

extern "C" void kernel_launch(void* const* d_in, const int* in_sizes, int n_in,
                              void* d_out, int out_size, void* d_ws, size_t ws_size,
                              hipStream_t stream) {
    const float* x   = (const float*)d_in[0];   // [N,128]
    const int*   ei  = (const int*)  d_in[1];   // [2,E]
    const int*   nei = (const int*)  d_in[2];   // [2,E]
    const float* W   = (const float*)d_in[3];   // [128,64]
    const float* b   = (const float*)d_in[4];   // [64]
    const float* Wc  = (const float*)d_in[5];   // [128,2]
    const float* bc  = (const float*)d_in[6];   // [2]

    // workspace (ints): end = 3901184 + 98*17408 = 5607168 ints = 22.4 MB
    int*      wsI    = (int*)d_ws;
    float*    dinv   = (float*)wsI;              // N          [0, 100352)
    unsigned* xwsh   = (unsigned*)(wsI + 100352);// N*32 bf16x2 [100352, 3300352)
    float*    pq     = (float*)(wsI + 3300352);  // N*4        [3300352, 3700352)
    int*      cursor = wsI + 3700352;            // NSB        [3700352, 3700480)
    int*      rowbeg = wsI + 3700480;            // N          [3700480, 3800832)
    int*      rowend = wsI + 3800832;            // N          [3800832, 3901184)
    int*      sbuf   = wsI + 3901184;            // NSB*SCAP

    const int B = 256;
    zero_kernel<<<1, B, 0, stream>>>(cursor);
    sorta_kernel<<<NABLK, B, 0, stream>>>(ei, cursor, sbuf);
    sortb_kernel<<<NSB, B, 0, stream>>>(cursor, sbuf, dinv, rowbeg, rowend);
    xws_kernel<<<(N_NODES + XN - 1) / XN, B, 0, stream>>>(x, W, dinv, xwsh);
    aggnode_kernel<<<(N_NODES + 3) / 4, B, 0, stream>>>(rowbeg, rowend, sbuf, dinv,
                                                        xwsh, b, Wc, bc, (float4*)pq);
    edge_kernel<<<(N_EDGES + B - 1) / B, B, 0, stream>>>(ei, nei, (const float4*)pq,
                                                         (float4*)d_out);
}

// Round 8
// 254.618 us; speedup vs baseline: 3.3745x; 1.0628x over previous
//
#include <hip/hip_runtime.h>

#define N_NODES 100000
#define N_EDGES 1600000
#define IN_C    128
#define OUT_C   64

#define SB_NODES 512                               // nodes per super-bucket
#define NSB  ((N_NODES + SB_NODES - 1) / SB_NODES) // 196
#define SCAP 9216                                  // mean 8163, +11 sigma
#define ACHUNK 4096                                // edges per sorta block
#define NABLK ((N_EDGES + ACHUNK - 1) / ACHUNK)    // 391

// ---- bf16x2 helpers ----
__device__ inline unsigned pack_bf16x2(float lo, float hi) {
    unsigned a = __float_as_uint(lo), b2 = __float_as_uint(hi);
    a  += 0x7fff + ((a  >> 16) & 1);               // RNE
    b2 += 0x7fff + ((b2 >> 16) & 1);
    return (a >> 16) | (b2 & 0xffff0000u);
}
__device__ inline float bf_lo(unsigned v) { return __uint_as_float(v << 16); }
__device__ inline float bf_hi(unsigned v) { return __uint_as_float(v & 0xffff0000u); }

// ---------------- zero super-bucket cursors ----------------
__global__ void zero_kernel(int* __restrict__ cursor) {
    int i = blockIdx.x * blockDim.x + threadIdx.x;
    if (i < NSB) cursor[i] = 0;
}

// ------ pass A: partition edges into 196 coarse dst-buckets (512 nodes) -----
// entry = s*512 + (d & 511); per-wave private histograms kill LDS-atomic
// contention; chunked reservations keep store-line sharing minimal.
__global__ __launch_bounds__(256) void sorta_kernel(const int* __restrict__ ei,
                                                    int* __restrict__ cursor,
                                                    int* __restrict__ sb) {
    __shared__ int histW[4][NSB];
    __shared__ int base_[NSB];
    __shared__ int cur[NSB];
    const int t = threadIdx.x, w = t >> 6;
    const long long e0 = (long long)blockIdx.x * ACHUNK;
    for (int i = t; i < 4 * NSB; i += 256) (&histW[0][0])[i] = 0;
    __syncthreads();
    const int* dsts = ei + N_EDGES;
#pragma unroll
    for (int k = 0; k < ACHUNK / 1024; ++k) {
        long long i4 = e0 / 4 + t + k * 256;
        if (i4 * 4 + 3 < N_EDGES) {
            int4 d = *(const int4*)&dsts[i4 * 4];
            atomicAdd(&histW[w][d.x >> 9], 1);
            atomicAdd(&histW[w][d.y >> 9], 1);
            atomicAdd(&histW[w][d.z >> 9], 1);
            atomicAdd(&histW[w][d.w >> 9], 1);
        }
    }
    __syncthreads();
    if (t < NSB) {
        int c = histW[0][t] + histW[1][t] + histW[2][t] + histW[3][t];
        base_[t] = c ? atomicAdd(&cursor[t], c) : 0;
        cur[t] = 0;
    }
    __syncthreads();
#pragma unroll
    for (int k = 0; k < ACHUNK / 1024; ++k) {
        long long i4 = e0 / 4 + t + k * 256;
        if (i4 * 4 + 3 < N_EDGES) {
            int4 s4 = *(const int4*)&ei[i4 * 4];
            int4 d4 = *(const int4*)&dsts[i4 * 4];
            int sv[4] = {s4.x, s4.y, s4.z, s4.w};
            int dv[4] = {d4.x, d4.y, d4.z, d4.w};
#pragma unroll
            for (int j = 0; j < 4; ++j) {
                int bk = dv[j] >> 9;
                int pos = base_[bk] + atomicAdd(&cur[bk], 1);
                if (pos < SCAP)
                    sb[bk * SCAP + pos] = sv[j] * SB_NODES + (dv[j] & (SB_NODES - 1));
            }
        }
    }
}

// ------ pass B: per coarse bucket, LDS counting sort by node -> CSR ---------
__global__ __launch_bounds__(256) void sortb_kernel(const int* __restrict__ cursor,
                                                    int* __restrict__ sb,
                                                    float* __restrict__ dinv,
                                                    int* __restrict__ rowbeg,
                                                    int* __restrict__ rowend) {
    __shared__ int hist[SB_NODES];
    __shared__ int pref[SB_NODES + 1];
    __shared__ int cur[SB_NODES];
    __shared__ int sc[256];
    __shared__ int sorted[SCAP];                   // 36.9 KB
    const int t = threadIdx.x, b = blockIdx.x;
    for (int k = t; k < SB_NODES; k += 256) { hist[k] = 0; cur[k] = 0; }
    __syncthreads();
    int m = cursor[b]; if (m > SCAP) m = SCAP;
    int* bb = sb + b * SCAP;
    for (int i = t; i < m; i += 256) atomicAdd(&hist[bb[i] & (SB_NODES - 1)], 1);
    __syncthreads();
    int c0 = hist[2 * t], c1 = hist[2 * t + 1];
    int tsum = c0 + c1;
    sc[t] = tsum;
    __syncthreads();
    for (int off = 1; off < 256; off <<= 1) {      // Hillis-Steele inclusive
        int u = (t >= off) ? sc[t - off] : 0;
        __syncthreads();
        sc[t] += u;
        __syncthreads();
    }
    int excl = sc[t] - tsum;
    pref[2 * t]     = excl;
    pref[2 * t + 1] = excl + c0;
    if (t == 255) pref[SB_NODES] = sc[255];
    __syncthreads();
    for (int i = t; i < m; i += 256) {
        int e = bb[i];
        int dl = e & (SB_NODES - 1);
        int pos = pref[dl] + atomicAdd(&cur[dl], 1);
        sorted[pos] = e >> 9;                      // plain src id
    }
    __syncthreads();
    for (int i = t; i < m; i += 256) bb[i] = sorted[i];   // coalesced writeback
    for (int k = t; k < SB_NODES; k += 256) {
        int n = b * SB_NODES + k;
        if (n < N_NODES) {
            rowbeg[n] = b * SCAP + pref[k];
            rowend[n] = b * SCAP + pref[k + 1];
            dinv[n]   = rsqrtf((float)hist[k] + 1.0f);    // +1 self-loop
        }
    }
}

// ------- xws = bf16( dinv[n] * (x @ W) ) : 32 nodes/block, 128 B rows -------
#define XN  32
#define SXS 132
__global__ __launch_bounds__(256) void xws_kernel(const float* __restrict__ x,
                                                  const float* __restrict__ W,
                                                  const float* __restrict__ dinv,
                                                  unsigned* __restrict__ xwsh) {
    __shared__ float sW[IN_C * OUT_C];     // 32 KB
    __shared__ float sx[XN * SXS];         // 16.9 KB
    const int t = threadIdx.x;
    const int n0 = blockIdx.x * XN;
    const float4* W4 = (const float4*)W;
    float4* sW4 = (float4*)sW;
#pragma unroll
    for (int k = 0; k < 8; ++k) sW4[t + k * 256] = W4[t + k * 256];
#pragma unroll
    for (int k = 0; k < 4; ++k) {
        int idx = (t + k * 256) * 4;
        int r = idx >> 7, kk = idx & 127;
        int n = n0 + r;
        float4 v = (n < N_NODES) ? *(const float4*)&x[(long long)n * IN_C + kk]
                                 : make_float4(0.f, 0.f, 0.f, 0.f);
        *(float4*)&sx[r * SXS + kk] = v;
    }
    __syncthreads();
    const int r  = t >> 4;
    const int cq = (t & 15) << 2;
    float4 a0 = make_float4(0.f,0.f,0.f,0.f), a1 = a0;
#pragma unroll 8
    for (int k = 0; k < IN_C; ++k) {
        float x0 = sx[r * SXS + k];
        float x1 = sx[(r + 16) * SXS + k];
        float4 wv = *(const float4*)&sW[(k << 6) + cq];
        a0.x = fmaf(x0, wv.x, a0.x); a0.y = fmaf(x0, wv.y, a0.y);
        a0.z = fmaf(x0, wv.z, a0.z); a0.w = fmaf(x0, wv.w, a0.w);
        a1.x = fmaf(x1, wv.x, a1.x); a1.y = fmaf(x1, wv.y, a1.y);
        a1.z = fmaf(x1, wv.z, a1.z); a1.w = fmaf(x1, wv.w, a1.w);
    }
    int na = n0 + r, nb = n0 + r + 16;
    if (na < N_NODES) {
        float di = dinv[na];
        uint2 o = make_uint2(pack_bf16x2(a0.x * di, a0.y * di),
                             pack_bf16x2(a0.z * di, a0.w * di));
        *(uint2*)&xwsh[(long long)na * 32 + ((t & 15) << 1)] = o;
    }
    if (nb < N_NODES) {
        float di = dinv[nb];
        uint2 o = make_uint2(pack_bf16x2(a1.x * di, a1.y * di),
                             pack_bf16x2(a1.z * di, a1.w * di));
        *(uint2*)&xwsh[(long long)nb * 32 + ((t & 15) << 1)] = o;
    }
}

// ------- pull aggregation + fused epilogue: wave per node ------------------
// srcs indices are wave-uniform -> scalar loads (no shfl broadcast); lanes
// 0-31 gather edge 2u's 128B bf16 row, lanes 32-63 edge 2u+1's (one cndmask).
__global__ __launch_bounds__(256) void aggnode_kernel(
    const int* __restrict__ rowbeg, const int* __restrict__ rowend,
    const int* __restrict__ srcs, const float* __restrict__ dinv,
    const unsigned* __restrict__ xwsh, const float* __restrict__ b,
    const float* __restrict__ Wc, const float* __restrict__ bc,
    float2* __restrict__ p, float2* __restrict__ q) {
    const int lane = threadIdx.x & 63;
    int node = __builtin_amdgcn_readfirstlane(blockIdx.x * 4 + (threadIdx.x >> 6));
    const int beg = rowbeg[node], end = rowend[node];   // scalar loads
    const int half = lane >> 5, hl = lane & 31;
    float ax0 = 0.f, ay0 = 0.f, ax1 = 0.f, ay1 = 0.f;
    float ax2 = 0.f, ay2 = 0.f, ax3 = 0.f, ay3 = 0.f;
    int i = beg;
    for (; i + 7 < end; i += 8) {                  // 4 dual-row loads in flight
        int s0 = srcs[i + 0], s1 = srcs[i + 1], s2 = srcs[i + 2], s3 = srcs[i + 3];
        int s4 = srcs[i + 4], s5 = srcs[i + 5], s6 = srcs[i + 6], s7 = srcs[i + 7];
        unsigned v0 = xwsh[(half ? s1 : s0) * 32 + hl];
        unsigned v1 = xwsh[(half ? s3 : s2) * 32 + hl];
        unsigned v2 = xwsh[(half ? s5 : s4) * 32 + hl];
        unsigned v3 = xwsh[(half ? s7 : s6) * 32 + hl];
        ax0 += bf_lo(v0); ay0 += bf_hi(v0);
        ax1 += bf_lo(v1); ay1 += bf_hi(v1);
        ax2 += bf_lo(v2); ay2 += bf_hi(v2);
        ax3 += bf_lo(v3); ay3 += bf_hi(v3);
    }
    for (; i + 1 < end; i += 2) {                  // pair tail
        int sa = srcs[i], sb2 = srcs[i + 1];
        unsigned v = xwsh[(half ? sb2 : sa) * 32 + hl];
        ax0 += bf_lo(v); ay0 += bf_hi(v);
    }
    if (i < end) {                                 // single tail (half 0 only)
        int s = srcs[i];
        unsigned v = xwsh[s * 32 + hl];
        if (!half) { ax1 += bf_lo(v); ay1 += bf_hi(v); }
    }
    float ax = (ax0 + ax1) + (ax2 + ax3);
    float ay = (ay0 + ay1) + (ay2 + ay3);
    ax += __shfl(ax, hl + 32);                     // combine halves (lanes 0-31)
    ay += __shfl(ay, hl + 32);
    unsigned vs = xwsh[node * 32 + hl];            // self-loop (dinv folded)
    ax += bf_lo(vs); ay += bf_hi(vs);
    float di = dinv[node];
    float2 b2 = ((const float2*)b)[hl];
    float h0 = fmaxf(fmaf(di, ax, b2.x), 0.f);
    float h1 = fmaxf(fmaf(di, ay, b2.y), 0.f);
    float4 wcs = ((const float4*)Wc)[hl];
    float4 wcd = ((const float4*)(Wc + 2 * OUT_C))[hl];
    float p0 = h0 * wcs.x + h1 * wcs.z;
    float p1 = h0 * wcs.y + h1 * wcs.w;
    float q0 = h0 * wcd.x + h1 * wcd.z;
    float q1 = h0 * wcd.y + h1 * wcd.w;
#pragma unroll
    for (int off = 16; off; off >>= 1) {           // width-32 reduce (lanes 0-31)
        p0 += __shfl_down(p0, off); p1 += __shfl_down(p1, off);
        q0 += __shfl_down(q0, off); q1 += __shfl_down(q1, off);
    }
    if (lane == 0) {
        p[node] = make_float2(p0 + bc[0], p1 + bc[1]);
        q[node] = make_float2(q0, q1);
    }
}

// ------------ edge outputs: out[e] = p[src] + q[dst], 4 edges/thread --------
__global__ void edge_kernel(const int* __restrict__ ei, const int* __restrict__ nei,
                            const float2* __restrict__ p, const float2* __restrict__ q,
                            float4* __restrict__ out4) {
    int idx = blockIdx.x * blockDim.x + threadIdx.x;
    if (idx >= 2 * N_EDGES / 4) return;
    int e4 = idx * 4;
    const int *S, *D;
    int off;
    if (e4 < N_EDGES) { S = ei;  D = ei  + N_EDGES; off = e4; }
    else              { S = nei; D = nei + N_EDGES; off = e4 - N_EDGES; }
    int4 s4 = *(const int4*)&S[off];
    int4 d4 = *(const int4*)&D[off];
    float2 pa = p[s4.x], qa = q[d4.x];
    float2 pb = p[s4.y], qb = q[d4.y];
    float2 pc = p[s4.z], qc = q[d4.z];
    float2 pd = p[s4.w], qd = q[d4.w];
    out4[idx * 2]     = make_float4(pa.x + qa.x, pa.y + qa.y, pb.x + qb.x, pb.y + qb.y);
    out4[idx * 2 + 1] = make_float4(pc.x + qc.x, pc.y + qc.y, pd.x + qd.x, pd.y + qd.y);
}

extern "C" void kernel_launch(void* const* d_in, const int* in_sizes, int n_in,
                              void* d_out, int out_size, void* d_ws, size_t ws_size,
                              hipStream_t stream) {
    const float* x   = (const float*)d_in[0];   // [N,128]
    const int*   ei  = (const int*)  d_in[1];   // [2,E]
    const int*   nei = (const int*)  d_in[2];   // [2,E]
    const float* W   = (const float*)d_in[3];   // [128,64]
    const float* b   = (const float*)d_in[4];   // [64]
    const float* Wc  = (const float*)d_in[5];   // [128,2]
    const float* bc  = (const float*)d_in[6];   // [2]

    // workspace (ints): end = 3902720 + 196*9216 = 5709056 ints = 22.8 MB
    int*      wsI    = (int*)d_ws;
    float*    dinv   = (float*)wsI;              // N           [0, 100352)
    unsigned* xwsh   = (unsigned*)(wsI + 100352);// N*32 bf16x2 [100352, 3300352)
    float*    p      = (float*)(wsI + 3300352);  // N*2         [3300352, 3501056)
    float*    q      = (float*)(wsI + 3501056);  // N*2         [3501056, 3701760)
    int*      cursor = wsI + 3701760;            // NSB         [3701760, 3702016)
    int*      rowbeg = wsI + 3702016;            // N           [3702016, 3802368)
    int*      rowend = wsI + 3802368;            // N           [3802368, 3902720)
    int*      sbuf   = wsI + 3902720;            // NSB*SCAP

    const int B = 256;
    zero_kernel<<<1, B, 0, stream>>>(cursor);
    sorta_kernel<<<NABLK, B, 0, stream>>>(ei, cursor, sbuf);
    sortb_kernel<<<NSB, B, 0, stream>>>(cursor, sbuf, dinv, rowbeg, rowend);
    xws_kernel<<<(N_NODES + XN - 1) / XN, B, 0, stream>>>(x, W, dinv, xwsh);
    aggnode_kernel<<<N_NODES / 4, B, 0, stream>>>(rowbeg, rowend, sbuf, dinv, xwsh,
                                                  b, Wc, bc, (float2*)p, (float2*)q);
    edge_kernel<<<(2 * N_EDGES / 4 + B - 1) / B, B, 0, stream>>>(
        ei, nei, (const float2*)p, (const float2*)q, (float4*)d_out);
}